// Round 1
// baseline (9643.118 us; speedup 1.0000x reference)
//
#include <hip/hip_runtime.h>
#include <hip/hip_bf16.h>

// ---------- types ----------
typedef __attribute__((ext_vector_type(8))) short  s16x8;
typedef __attribute__((ext_vector_type(4))) float  f32x4;
typedef __attribute__((ext_vector_type(4))) unsigned short u16x4;

#define B_  64
#define T_  1024
#define I_  512
#define H_  1024
#define O_  512
#define MT_ 65536   // B_*T_

// ---------- helpers ----------
__device__ __forceinline__ unsigned short f2bf(float f) {
    unsigned u = __builtin_bit_cast(unsigned, f);
    u += 0x7FFFu + ((u >> 16) & 1u);
    return (unsigned short)(u >> 16);
}
__device__ __forceinline__ float bf2f(unsigned short h) {
    return __builtin_bit_cast(float, ((unsigned)h) << 16);
}
__device__ __forceinline__ void store_out(float* p, float v) { *p = v; }
__device__ __forceinline__ void store_out(unsigned short* p, float v) { *p = f2bf(v); }
__device__ __forceinline__ float to_f32(float v) { return v; }
__device__ __forceinline__ float to_f32(unsigned short v) { return bf2f(v); }

#define GL2LDS16(gp, lp) __builtin_amdgcn_global_load_lds( \
    (const __attribute__((address_space(1))) void*)(gp),   \
    (__attribute__((address_space(3))) void*)(lp), 16, 0, 0)

// ---------- conversion kernels ----------
__global__ void cvt_x(const float* __restrict__ src, unsigned short* __restrict__ dst, int n) {
    int stride = gridDim.x * blockDim.x * 4;
    for (int i = (blockIdx.x * blockDim.x + threadIdx.x) * 4; i < n; i += stride) {
        const float4 v = *(const float4*)(src + i);
        u16x4 o;
        o.x = f2bf(v.x); o.y = f2bf(v.y); o.z = f2bf(v.z); o.w = f2bf(v.w);
        *(u16x4*)(dst + i) = o;
    }
}

// dst[c][r] = bf16(src[row_off + r][c]);  src region [SR,SC] row-major -> dst [SC,SR]
__global__ void cvt_t(const float* __restrict__ src, unsigned short* __restrict__ dst,
                      int SR, int SC, int row_off) {
    __shared__ unsigned short tile[32][33];
    int c0 = blockIdx.x * 32, r0 = blockIdx.y * 32;
    int tx = threadIdx.x, ty = threadIdx.y;
    #pragma unroll
    for (int i = 0; i < 32; i += 8)
        tile[ty + i][tx] = f2bf(src[(size_t)(row_off + r0 + ty + i) * SC + c0 + tx]);
    __syncthreads();
    #pragma unroll
    for (int i = 0; i < 32; i += 8)
        dst[(size_t)(c0 + ty + i) * SR + r0 + tx] = tile[tx][ty + i];
}

// ---------- generic bf16 MFMA GEMM: C[M,N] = act(A[M,K] @ BT[N,K]^T + bias) ----------
// m97-style: 128x128 tile, BK=32, 4 waves (2x2), global_load_lds(16B), linear LDS.
template<typename OutT, bool LRELU, bool SCATTER>
__global__ __launch_bounds__(256)
void gemm_bf16(const unsigned short* __restrict__ A,
               const unsigned short* __restrict__ BT,
               const float* __restrict__ bias,
               OutT* __restrict__ C, int M, int K, int N)
{
    __shared__ unsigned short As[4096]; // [128][32]
    __shared__ unsigned short Bs[4096]; // [128][32]
    const int tid = threadIdx.x, lane = tid & 63, wid = tid >> 6;
    const int wr = wid >> 1, wc = wid & 1;
    const int m0 = blockIdx.x * 128, n0 = blockIdx.y * 128;

    f32x4 acc[4][4] = {};

    const int c = wid * 2;               // this wave's first staging chunk (of 8)
    const int srow = lane >> 2;          // 0..15 within chunk
    const int scol = (lane & 3) * 8;     // 0,8,16,24
    const unsigned short* Ag0 = A  + (size_t)(m0 + c * 16 + srow) * K + scol;
    const unsigned short* Ag1 = A  + (size_t)(m0 + c * 16 + 16 + srow) * K + scol;
    const unsigned short* Bg0 = BT + (size_t)(n0 + c * 16 + srow) * K + scol;
    const unsigned short* Bg1 = BT + (size_t)(n0 + c * 16 + 16 + srow) * K + scol;

    for (int k0 = 0; k0 < K; k0 += 32) {
        __syncthreads();
        GL2LDS16(Ag0 + k0, As + c * 512);
        GL2LDS16(Ag1 + k0, As + (c + 1) * 512);
        GL2LDS16(Bg0 + k0, Bs + c * 512);
        GL2LDS16(Bg1 + k0, Bs + (c + 1) * 512);
        __syncthreads();

        s16x8 af[4], bfr[4];
        #pragma unroll
        for (int i = 0; i < 4; i++)
            af[i] = *(const s16x8*)(As + (wr * 64 + i * 16 + (lane & 15)) * 32 + (lane >> 4) * 8);
        #pragma unroll
        for (int j = 0; j < 4; j++)
            bfr[j] = *(const s16x8*)(Bs + (wc * 64 + j * 16 + (lane & 15)) * 32 + (lane >> 4) * 8);
        #pragma unroll
        for (int i = 0; i < 4; i++)
            #pragma unroll
            for (int j = 0; j < 4; j++)
                acc[i][j] = __builtin_amdgcn_mfma_f32_16x16x32_bf16(af[i], bfr[j], acc[i][j], 0, 0, 0);
    }

    #pragma unroll
    for (int j = 0; j < 4; j++) {
        const int n = n0 + wc * 64 + j * 16 + (lane & 15);
        const float bv = bias[n];
        #pragma unroll
        for (int i = 0; i < 4; i++) {
            #pragma unroll
            for (int r = 0; r < 4; r++) {
                const int m = m0 + wr * 64 + i * 16 + (lane >> 4) * 4 + r;
                if (m < M) {
                    float v = acc[i][j][r] + bv;
                    if (LRELU) v = v >= 0.f ? v : 0.01f * v;
                    // SCATTER: row m = b*T_+t  -> t-major row t*B_+b
                    size_t row = SCATTER ? (size_t)((m & (T_ - 1)) * B_ + (m >> 10)) : (size_t)m;
                    store_out(&C[row * N + n], v);
                }
            }
        }
    }
}

// ---------- persistent scan kernel ----------
// 64 WGs x 256 threads. WG owns 16 cols; Wbot^T slice resident in LDS.
// h ping-pongs in global bf16 [2][64][1024]; pre is t-major [T][B][H].
template<typename PreT>
__global__ __launch_bounds__(256)
void rnn_scan(const unsigned short* __restrict__ WbotT,
              const PreT* __restrict__ pre,
              unsigned short* __restrict__ hbuf,
              unsigned* __restrict__ bar)
{
    __shared__ unsigned short Ws[16 * 1032]; // [16][1024+8] padded
    const int tid = threadIdx.x, lane = tid & 63, wid = tid >> 6;
    const int n0 = blockIdx.x * 16;

    for (int idx = tid; idx < 16 * 128; idx += 256) {
        int r = idx >> 7, cc = (idx & 127) * 8;
        *(s16x8*)(Ws + r * 1032 + cc) = *(const s16x8*)(WbotT + (size_t)(n0 + r) * H_ + cc);
    }
    __syncthreads();

    const int mrow = wid * 16 + (lane & 15);
    const int hi = lane >> 4;               // 0..3
    const int nn = n0 + (lane & 15);
    const int nblk = gridDim.x;
    unsigned target = 0;

    for (int t = 0; t < T_; ++t) {
        const unsigned short* hc = hbuf + ((t & 1) << 16);
        unsigned short* hn = hbuf + (((t + 1) & 1) << 16);

        // prefetch pre_t values for epilogue (contiguous t-major block)
        float pv[4];
        #pragma unroll
        for (int r = 0; r < 4; r++) {
            int b = wid * 16 + hi * 4 + r;
            pv[r] = to_f32(pre[((size_t)t * B_ + b) * H_ + nn]);
        }

        f32x4 acc = {0.f, 0.f, 0.f, 0.f};
        const unsigned short* hrow = hc + mrow * H_ + hi * 8;
        #pragma unroll 8
        for (int kk = 0; kk < 32; ++kk) {
            s16x8 af = *(const s16x8*)(hrow + kk * 32);
            s16x8 bf = *(const s16x8*)(Ws + (lane & 15) * 1032 + kk * 32 + hi * 8);
            acc = __builtin_amdgcn_mfma_f32_16x16x32_bf16(af, bf, acc, 0, 0, 0);
        }

        #pragma unroll
        for (int r = 0; r < 4; r++) {
            int b = wid * 16 + hi * 4 + r;
            float v = acc[r] + pv[r];
            v = v >= 0.f ? v : 0.01f * v;
            hn[b * H_ + nn] = f2bf(v);
        }

        // device-wide barrier (monotonic counter; all 64 blocks are co-resident)
        target += nblk;
        __syncthreads();
        if (tid == 0) {
            __threadfence();
            atomicAdd(bar, 1u);
            while (__hip_atomic_load(bar, __ATOMIC_ACQUIRE, __HIP_MEMORY_SCOPE_AGENT) < target)
                __builtin_amdgcn_s_sleep(2);
        }
        __syncthreads();
    }
}

// ---------- launch ----------
extern "C" void kernel_launch(void* const* d_in, const int* in_sizes, int n_in,
                              void* d_out, int out_size, void* d_ws, size_t ws_size,
                              hipStream_t stream)
{
    const float* x     = (const float*)d_in[0];
    const float* W_in  = (const float*)d_in[1];
    const float* b_in  = (const float*)d_in[2];
    const float* W_h   = (const float*)d_in[3];
    const float* b_h   = (const float*)d_in[4];
    const float* W_out = (const float*)d_in[5];
    const float* b_out = (const float*)d_in[6];
    float* out = (float*)d_out;

    char* ws = (char*)d_ws;
    size_t off = 0;
    auto alloc = [&](size_t bytes) { void* p = ws + off; off += (bytes + 255) & ~(size_t)255; return p; };

    unsigned short* Xb    = (unsigned short*)alloc((size_t)MT_ * I_ * 2); // bf16 X
    unsigned short* WinT  = (unsigned short*)alloc((size_t)H_ * I_ * 2);  // [H][I]
    unsigned short* WtopT = (unsigned short*)alloc((size_t)H_ * H_ * 2);  // [H][H]
    unsigned short* WbotT = (unsigned short*)alloc((size_t)H_ * H_ * 2);  // [H][H]
    unsigned short* WoutT = (unsigned short*)alloc((size_t)O_ * H_ * 2);  // [O][H]
    unsigned short* Abuf  = (unsigned short*)alloc((size_t)MT_ * H_ * 2); // bf16 h_new_all
    unsigned short* hbuf  = (unsigned short*)alloc((size_t)2 * B_ * H_ * 2);
    unsigned*       bar   = (unsigned*)alloc(256);
    void* pre = ws + off;
    const bool pre_f32 = (off + (size_t)MT_ * H_ * 4) <= ws_size;

    hipMemsetAsync(hbuf, 0, (size_t)2 * B_ * H_ * 2, stream);
    hipMemsetAsync(bar, 0, 256, stream);

    cvt_x<<<2048, 256, 0, stream>>>(x, Xb, MT_ * I_);
    dim3 tb(32, 8);
    cvt_t<<<dim3(H_ / 32, I_ / 32), tb, 0, stream>>>(W_in,  WinT,  I_, H_, 0);
    cvt_t<<<dim3(H_ / 32, H_ / 32), tb, 0, stream>>>(W_h,   WtopT, H_, H_, 0);
    cvt_t<<<dim3(H_ / 32, H_ / 32), tb, 0, stream>>>(W_h,   WbotT, H_, H_, H_);
    cvt_t<<<dim3(O_ / 32, H_ / 32), tb, 0, stream>>>(W_out, WoutT, H_, O_, 0);

    // GEMM1: A = lrelu(X @ W_in + b_in)   [MT, H] bf16
    gemm_bf16<unsigned short, true, false>
        <<<dim3(MT_ / 128, H_ / 128), 256, 0, stream>>>(Xb, WinT, b_in, Abuf, MT_, I_, H_);

    // GEMM2: pre = A @ Wtop + b_h   written t-major [T][B][H]
    if (pre_f32) {
        gemm_bf16<float, false, true>
            <<<dim3(MT_ / 128, H_ / 128), 256, 0, stream>>>(Abuf, WtopT, b_h, (float*)pre, MT_, H_, H_);
        rnn_scan<float><<<64, 256, 0, stream>>>(WbotT, (const float*)pre, hbuf, bar);
    } else {
        gemm_bf16<unsigned short, false, true>
            <<<dim3(MT_ / 128, H_ / 128), 256, 0, stream>>>(Abuf, WtopT, b_h, (unsigned short*)pre, MT_, H_, H_);
        rnn_scan<unsigned short><<<64, 256, 0, stream>>>(WbotT, (const unsigned short*)pre, hbuf, bar);
    }

    // final: out = h_final @ W_out + b_out   (h_final = hbuf[0], M=64 guarded)
    gemm_bf16<float, false, false>
        <<<dim3(1, O_ / 128), 256, 0, stream>>>(hbuf, WoutT, b_out, out, B_, H_, O_);
}

// Round 2
// 7013.038 us; speedup vs baseline: 1.3750x; 1.3750x over previous
//
#include <hip/hip_runtime.h>
#include <hip/hip_bf16.h>

// ---------- types ----------
typedef __attribute__((ext_vector_type(8))) short  s16x8;
typedef __attribute__((ext_vector_type(4))) float  f32x4;
typedef __attribute__((ext_vector_type(4))) unsigned short u16x4;

#define B_  64
#define T_  1024
#define I_  512
#define H_  1024
#define O_  512
#define MT_ 65536   // B_*T_

// scan decomposition: 4 row-groups x 16 col-slices
#define RG_   4
#define CS_   16
#define WSLD  1048   // LDS row stride (shorts): 2096B, 16B-aligned, 2-way-bank-free

// ---------- helpers ----------
__device__ __forceinline__ unsigned short f2bf(float f) {
    unsigned u = __builtin_bit_cast(unsigned, f);
    u += 0x7FFFu + ((u >> 16) & 1u);
    return (unsigned short)(u >> 16);
}
__device__ __forceinline__ float bf2f(unsigned short h) {
    return __builtin_bit_cast(float, ((unsigned)h) << 16);
}
__device__ __forceinline__ void store_out(float* p, float v) { *p = v; }
__device__ __forceinline__ void store_out(unsigned short* p, float v) { *p = f2bf(v); }
__device__ __forceinline__ float to_f32(float v) { return v; }
__device__ __forceinline__ float to_f32(unsigned short v) { return bf2f(v); }

#define GL2LDS16(gp, lp) __builtin_amdgcn_global_load_lds( \
    (const __attribute__((address_space(1))) void*)(gp),   \
    (__attribute__((address_space(3))) void*)(lp), 16, 0, 0)

// ---------- conversion kernels ----------
__global__ void cvt_x(const float* __restrict__ src, unsigned short* __restrict__ dst, int n) {
    int stride = gridDim.x * blockDim.x * 4;
    for (int i = (blockIdx.x * blockDim.x + threadIdx.x) * 4; i < n; i += stride) {
        const float4 v = *(const float4*)(src + i);
        u16x4 o;
        o.x = f2bf(v.x); o.y = f2bf(v.y); o.z = f2bf(v.z); o.w = f2bf(v.w);
        *(u16x4*)(dst + i) = o;
    }
}

// dst[c][r] = bf16(src[row_off + r][c]);  src region [SR,SC] row-major -> dst [SC,SR]
__global__ void cvt_t(const float* __restrict__ src, unsigned short* __restrict__ dst,
                      int SR, int SC, int row_off) {
    __shared__ unsigned short tile[32][33];
    int c0 = blockIdx.x * 32, r0 = blockIdx.y * 32;
    int tx = threadIdx.x, ty = threadIdx.y;
    #pragma unroll
    for (int i = 0; i < 32; i += 8)
        tile[ty + i][tx] = f2bf(src[(size_t)(row_off + r0 + ty + i) * SC + c0 + tx]);
    __syncthreads();
    #pragma unroll
    for (int i = 0; i < 32; i += 8)
        dst[(size_t)(c0 + ty + i) * SR + r0 + tx] = tile[tx][ty + i];
}

// ---------- generic bf16 MFMA GEMM: C[M,N] = act(A[M,K] @ BT[N,K]^T + bias) ----------
template<typename OutT, bool LRELU, bool SCATTER>
__global__ __launch_bounds__(256)
void gemm_bf16(const unsigned short* __restrict__ A,
               const unsigned short* __restrict__ BT,
               const float* __restrict__ bias,
               OutT* __restrict__ C, int M, int K, int N)
{
    __shared__ unsigned short As[4096]; // [128][32]
    __shared__ unsigned short Bs[4096]; // [128][32]
    const int tid = threadIdx.x, lane = tid & 63, wid = tid >> 6;
    const int wr = wid >> 1, wc = wid & 1;
    const int m0 = blockIdx.x * 128, n0 = blockIdx.y * 128;

    f32x4 acc[4][4] = {};

    const int c = wid * 2;
    const int srow = lane >> 2;
    const int scol = (lane & 3) * 8;
    const unsigned short* Ag0 = A  + (size_t)(m0 + c * 16 + srow) * K + scol;
    const unsigned short* Ag1 = A  + (size_t)(m0 + c * 16 + 16 + srow) * K + scol;
    const unsigned short* Bg0 = BT + (size_t)(n0 + c * 16 + srow) * K + scol;
    const unsigned short* Bg1 = BT + (size_t)(n0 + c * 16 + 16 + srow) * K + scol;

    for (int k0 = 0; k0 < K; k0 += 32) {
        __syncthreads();
        GL2LDS16(Ag0 + k0, As + c * 512);
        GL2LDS16(Ag1 + k0, As + (c + 1) * 512);
        GL2LDS16(Bg0 + k0, Bs + c * 512);
        GL2LDS16(Bg1 + k0, Bs + (c + 1) * 512);
        __syncthreads();

        s16x8 af[4], bfr[4];
        #pragma unroll
        for (int i = 0; i < 4; i++)
            af[i] = *(const s16x8*)(As + (wr * 64 + i * 16 + (lane & 15)) * 32 + (lane >> 4) * 8);
        #pragma unroll
        for (int j = 0; j < 4; j++)
            bfr[j] = *(const s16x8*)(Bs + (wc * 64 + j * 16 + (lane & 15)) * 32 + (lane >> 4) * 8);
        #pragma unroll
        for (int i = 0; i < 4; i++)
            #pragma unroll
            for (int j = 0; j < 4; j++)
                acc[i][j] = __builtin_amdgcn_mfma_f32_16x16x32_bf16(af[i], bfr[j], acc[i][j], 0, 0, 0);
    }

    #pragma unroll
    for (int j = 0; j < 4; j++) {
        const int n = n0 + wc * 64 + j * 16 + (lane & 15);
        const float bv = bias[n];
        #pragma unroll
        for (int i = 0; i < 4; i++) {
            #pragma unroll
            for (int r = 0; r < 4; r++) {
                const int m = m0 + wr * 64 + i * 16 + (lane >> 4) * 4 + r;
                if (m < M) {
                    float v = acc[i][j][r] + bv;
                    if (LRELU) v = v >= 0.f ? v : 0.01f * v;
                    size_t row = SCATTER ? (size_t)((m & (T_ - 1)) * B_ + (m >> 10)) : (size_t)m;
                    store_out(&C[row * N + n], v);
                }
            }
        }
    }
}

// ---------- scan kernel: 64 blocks (4 row-groups x 16 col-slices), 256 thr ----------
// Per-producer monotonic flags; agent-scope (sc1) h exchange; Wbot^T slice in LDS.
template<typename PreT>
__global__ __launch_bounds__(256)
void rnn_scan2(const unsigned short* __restrict__ WbotT,
               const PreT* __restrict__ pre,      // [T][B][H]
               unsigned short* __restrict__ hbuf, // [2][B][H] bf16
               unsigned* __restrict__ flags)      // [RG_*CS_] at stride 16 u32
{
    __shared__ unsigned short Ws[64 * WSLD];      // [64 cols][1024 k]
    const int tid = threadIdx.x, lane = tid & 63, w = tid >> 6;
    const int rg = blockIdx.x >> 4;               // row-group (16 batch rows)
    const int cs = blockIdx.x & 15;               // col-slice (64 cols)
    const int row0 = rg * 16;
    const int n0 = cs * 64;

    for (int idx = tid; idx < 64 * 128; idx += 256) {
        int r = idx >> 7, ck = (idx & 127) * 8;
        *(s16x8*)(Ws + r * WSLD + ck) = *(const s16x8*)(WbotT + (size_t)(n0 + r) * H_ + ck);
    }
    __syncthreads();

    const int l15 = lane & 15, l4 = lane >> 4;
    const int myrow = row0 + l4 * 4;              // first of 4 output rows
    const int mycol = n0 + w * 16 + l15;          // output col
    const unsigned short* wsbase = Ws + (size_t)(w * 16 + l15) * WSLD + l4 * 8;
    const size_t ha_off = (size_t)(row0 + l15) * H_ + l4 * 8;

    float pv[4];
    #pragma unroll
    for (int r = 0; r < 4; r++)
        pv[r] = to_f32(pre[(size_t)(myrow + r) * H_ + mycol]);

    for (int t = 0; t < T_; ++t) {
        if (t) {
            if (w == 0) {
                const unsigned want = (unsigned)t;
                bool ok;
                do {
                    unsigned f = want;
                    if (lane < 16)
                        f = __hip_atomic_load(&flags[(rg * 16 + lane) * 16],
                                              __ATOMIC_RELAXED, __HIP_MEMORY_SCOPE_AGENT);
                    ok = (f >= want);
                } while (!__all(ok));
                __builtin_amdgcn_fence(__ATOMIC_ACQUIRE, "agent");
            }
            __syncthreads();
        }

        const unsigned short* hc = hbuf + ((t & 1) << 16);
        unsigned short*       hn = hbuf + (((t + 1) & 1) << 16);
        const unsigned short* ha = hc + ha_off;

        f32x4 a0 = {}, a1 = {}, a2 = {}, a3 = {};
        #pragma unroll
        for (int kk = 0; kk < 32; kk += 4) {
            s16x8 f0 = *(const s16x8*)(ha + (kk + 0) * 32);
            s16x8 f1 = *(const s16x8*)(ha + (kk + 1) * 32);
            s16x8 f2 = *(const s16x8*)(ha + (kk + 2) * 32);
            s16x8 f3 = *(const s16x8*)(ha + (kk + 3) * 32);
            s16x8 g0 = *(const s16x8*)(wsbase + (kk + 0) * 32);
            s16x8 g1 = *(const s16x8*)(wsbase + (kk + 1) * 32);
            s16x8 g2 = *(const s16x8*)(wsbase + (kk + 2) * 32);
            s16x8 g3 = *(const s16x8*)(wsbase + (kk + 3) * 32);
            a0 = __builtin_amdgcn_mfma_f32_16x16x32_bf16(f0, g0, a0, 0, 0, 0);
            a1 = __builtin_amdgcn_mfma_f32_16x16x32_bf16(f1, g1, a1, 0, 0, 0);
            a2 = __builtin_amdgcn_mfma_f32_16x16x32_bf16(f2, g2, a2, 0, 0, 0);
            a3 = __builtin_amdgcn_mfma_f32_16x16x32_bf16(f3, g3, a3, 0, 0, 0);
        }
        f32x4 acc = (a0 + a1) + (a2 + a3);

        #pragma unroll
        for (int r = 0; r < 4; r++) {
            float v = acc[r] + pv[r];
            v = v >= 0.f ? v : 0.01f * v;
            __hip_atomic_store(&hn[(size_t)(myrow + r) * H_ + mycol], f2bf(v),
                               __ATOMIC_RELAXED, __HIP_MEMORY_SCOPE_AGENT);
        }

        // prefetch next step's pre into regs (overlaps flag wait)
        const int tn = (t + 1 < T_) ? t + 1 : t;
        #pragma unroll
        for (int r = 0; r < 4; r++)
            pv[r] = to_f32(pre[((size_t)tn * B_ + myrow + r) * H_ + mycol]);

        __syncthreads();  // drains all waves' h stores (vmcnt 0) before flagging
        if (tid == 0)
            __hip_atomic_store(&flags[(rg * 16 + cs) * 16], (unsigned)(t + 1),
                               __ATOMIC_RELEASE, __HIP_MEMORY_SCOPE_AGENT);
    }
}

// ---------- launch ----------
extern "C" void kernel_launch(void* const* d_in, const int* in_sizes, int n_in,
                              void* d_out, int out_size, void* d_ws, size_t ws_size,
                              hipStream_t stream)
{
    const float* x     = (const float*)d_in[0];
    const float* W_in  = (const float*)d_in[1];
    const float* b_in  = (const float*)d_in[2];
    const float* W_h   = (const float*)d_in[3];
    const float* b_h   = (const float*)d_in[4];
    const float* W_out = (const float*)d_in[5];
    const float* b_out = (const float*)d_in[6];
    float* out = (float*)d_out;

    char* ws = (char*)d_ws;
    size_t off = 0;
    auto alloc = [&](size_t bytes) { void* p = ws + off; off += (bytes + 255) & ~(size_t)255; return p; };

    unsigned short* Xb    = (unsigned short*)alloc((size_t)MT_ * I_ * 2);
    unsigned short* WinT  = (unsigned short*)alloc((size_t)H_ * I_ * 2);
    unsigned short* WtopT = (unsigned short*)alloc((size_t)H_ * H_ * 2);
    unsigned short* WbotT = (unsigned short*)alloc((size_t)H_ * H_ * 2);
    unsigned short* WoutT = (unsigned short*)alloc((size_t)O_ * H_ * 2);
    unsigned short* Abuf  = (unsigned short*)alloc((size_t)MT_ * H_ * 2);
    unsigned short* hbuf  = (unsigned short*)alloc((size_t)2 * B_ * H_ * 2);
    unsigned*       flags = (unsigned*)alloc(RG_ * CS_ * 16 * sizeof(unsigned));
    void* pre = ws + off;
    const bool pre_f32 = (off + (size_t)MT_ * H_ * 4) <= ws_size;

    hipMemsetAsync(hbuf, 0, (size_t)2 * B_ * H_ * 2, stream);
    hipMemsetAsync(flags, 0, RG_ * CS_ * 16 * sizeof(unsigned), stream);

    cvt_x<<<2048, 256, 0, stream>>>(x, Xb, MT_ * I_);
    dim3 tb(32, 8);
    cvt_t<<<dim3(H_ / 32, I_ / 32), tb, 0, stream>>>(W_in,  WinT,  I_, H_, 0);
    cvt_t<<<dim3(H_ / 32, H_ / 32), tb, 0, stream>>>(W_h,   WtopT, H_, H_, 0);
    cvt_t<<<dim3(H_ / 32, H_ / 32), tb, 0, stream>>>(W_h,   WbotT, H_, H_, H_);
    cvt_t<<<dim3(O_ / 32, H_ / 32), tb, 0, stream>>>(W_out, WoutT, H_, O_, 0);

    // GEMM1: A = lrelu(X @ W_in + b_in)   [MT, H] bf16
    gemm_bf16<unsigned short, true, false>
        <<<dim3(MT_ / 128, H_ / 128), 256, 0, stream>>>(Xb, WinT, b_in, Abuf, MT_, I_, H_);

    // GEMM2: pre = A @ Wtop + b_h   written t-major [T][B][H]
    if (pre_f32) {
        gemm_bf16<float, false, true>
            <<<dim3(MT_ / 128, H_ / 128), 256, 0, stream>>>(Abuf, WtopT, b_h, (float*)pre, MT_, H_, H_);
        rnn_scan2<float><<<RG_ * CS_, 256, 0, stream>>>(WbotT, (const float*)pre, hbuf, flags);
    } else {
        gemm_bf16<unsigned short, false, true>
            <<<dim3(MT_ / 128, H_ / 128), 256, 0, stream>>>(Abuf, WtopT, b_h, (unsigned short*)pre, MT_, H_, H_);
        rnn_scan2<unsigned short><<<RG_ * CS_, 256, 0, stream>>>(WbotT, (const unsigned short*)pre, hbuf, flags);
    }

    // final: out = h_final @ W_out + b_out
    gemm_bf16<float, false, false>
        <<<dim3(1, O_ / 128), 256, 0, stream>>>(hbuf, WoutT, b_out, out, B_, H_, O_);
}